// Round 12
// baseline (174.134 us; speedup 1.0000x reference)
//
#include <hip/hip_runtime.h>
#include <math.h>

#define D_MODEL 4096
#define N_EXP   64

typedef _Float16 half8 __attribute__((ext_vector_type(8)));
typedef float    f32x4 __attribute__((ext_vector_type(4)));

// ---------------------------------------------------------------------------
// Prep: W[64][4096] fp32 -> fragment-ordered fp16 hi/lo arrays (in d_ws).
// Ws = W*64; hi = fp16(Ws); lo = fp16((Ws-hi)*4096). Fragment order:
// element (kstep,nt,lane,j) at ((kstep*4+nt)*64+lane)*8+j, expert
// e = nt*16+(lane&15), k = kstep*32+(lane>>4)*8+j. (Verified R4-R11.)
// ---------------------------------------------------------------------------
__global__ __launch_bounds__(256)
void wprep_kernel(const float* __restrict__ W,
                  _Float16* __restrict__ whf, _Float16* __restrict__ wlf) {
    const int gid   = blockIdx.x * 256 + threadIdx.x;   // 0..32767
    const int lane  = gid & 63;
    const int ntk   = gid >> 6;
    const int nt    = ntk & 3;
    const int kstep = ntk >> 2;
    const int e  = nt * 16 + (lane & 15);
    const int k0 = kstep * 32 + (lane >> 4) * 8;

    const float* src = W + (size_t)e * D_MODEL + k0;
    float4 w0 = *(const float4*)(src);
    float4 w1 = *(const float4*)(src + 4);
    float wv[8] = {w0.x, w0.y, w0.z, w0.w, w1.x, w1.y, w1.z, w1.w};

    half8 hh, ll;
    #pragma unroll
    for (int j = 0; j < 8; ++j) {
        float ws = wv[j] * 64.0f;
        _Float16 h = (_Float16)ws;
        hh[j] = h;
        ll[j] = (_Float16)((ws - (float)h) * 4096.0f);
    }
    *(half8*)(whf + (size_t)gid * 8) = hh;
    *(half8*)(wlf + (size_t)gid * 8) = ll;
}

// global -> LDS direct (16B/lane, dest = wave-uniform base + lane*16)
#define GLD16(gp, lp) __builtin_amdgcn_global_load_lds( \
    (const __attribute__((address_space(1))) unsigned int*)(const void*)(gp), \
    (__attribute__((address_space(3))) unsigned int*)(void*)(lp), 16, 0, 0)

__device__ __forceinline__ void cvt_hilo(const float4 a, const float4 b,
                                         half8& hi, half8& lo) {
    float av[8] = {a.x, a.y, a.z, a.w, b.x, b.y, b.z, b.w};
    #pragma unroll
    for (int j = 0; j < 8; ++j) {
        _Float16 h = (_Float16)av[j];
        hi[j] = h;
        lo[j] = (_Float16)((av[j] - (float)h) * 4096.0f);
    }
}

#define MFMA16(A, B, C) __builtin_amdgcn_mfma_f32_16x16x32_f16(A, B, C, 0, 0, 0)

// ---------------------------------------------------------------------------
// Main: 256 thr = 4 waves x 16 tokens, 512 blocks (2/CU, 8 waves/CU).
// ZERO barriers: all staging is wave-private, sync is per-wave counted
// s_waitcnt vmcnt(N) only (steady N=20, FIFO-enumerated).
//  - A: wave-private LDS ring, 3 slots x 4KB (2 ksteps each). Coalesced
//    GLD16 slabs (4/group, 4 rows each, 8 reqs/instr). Source-side XOR
//    swizzle f(r)=(r&3)*2+((r>>2)&1) on the 16B-chunk index (permutes
//    within each row's 256B span -> coalescing intact) makes the fragment
//    ds_reads perfectly bank-balanced.
//  - B: per-wave register pipeline, depth 3 (96 VGPR), contiguous 1KB
//    loads; issued after the consuming MFMAs (in-order WAR safety).
// A aged 4 ksteps (~HBM lat), B aged 3 ksteps (>= L2 lat) at their waits.
// ---------------------------------------------------------------------------
__global__ __launch_bounds__(256, 2)
void router_kernel(const float* __restrict__ x,
                   const _Float16* __restrict__ whf,
                   const _Float16* __restrict__ wlf,
                   float* __restrict__ out, int ntok) {
    __shared__ __align__(16) float sA[4][3][1024];   // [wave][slot][2ks*16rows*64f] = 48 KiB

    const int tid  = threadIdx.x;
    const int w    = tid >> 6;
    const int l    = tid & 63;
    const int tok0 = blockIdx.x * 64;
    const int hi   = l >> 4;     // k-quarter
    const int r    = l & 15;     // token row within wave strip

    // A stage sources: slab j holds rows w*16+4j..+3; lane l -> row 4j+(l>>4),
    // fetches global chunk (l&15) ^ f(row) of that row's 256B group-span.
    const float* asrc[4];
    #pragma unroll
    for (int j = 0; j < 4; ++j) {
        const int row = tok0 + w * 16 + j * 4 + hi;
        const int csl = (l & 15) ^ (hi * 2 + (j & 1));
        asrc[j] = x + (size_t)row * D_MODEL + csl * 4;
    }

    // A read addresses: row r -> slab jp=r>>2, in-slab up=r&3; chunk
    // c = (p*8 + hi*2 (+0/1)) ^ f(r), f(r)=up*2+(jp&1); +p*32 floats, +slot*1024.
    const int jp = r >> 2, up = r & 3;
    const int fp = up * 2 + (jp & 1);
    const int c1 = (hi * 2) ^ fp;
    const float* rda = &sA[w][0][jp * 256 + up * 64 + c1 * 4];
    const float* rdb = &sA[w][0][jp * 256 + up * 64 + (c1 ^ 1) * 4];

    const _Float16* bh = whf + (size_t)l * 8;
    const _Float16* bl = wlf + (size_t)l * 8;

    f32x4 hh[4], cc[4];
    #pragma unroll
    for (int nt = 0; nt < 4; ++nt) { hh[nt] = (f32x4)0.0f; cc[nt] = (f32x4)0.0f; }

    half8 B0h[4], B0l[4], B1h[4], B1l[4], B2h[4], B2l[4];

#define LOADB(KS, BH, BL)                                                      \
    {                                                                          \
        const size_t o = (size_t)(KS) * 2048;                                  \
        _Pragma("unroll")                                                      \
        for (int nt = 0; nt < 4; ++nt) {                                       \
            BH[nt] = *(const half8*)(bh + o + nt * 512);                       \
            BL[nt] = *(const half8*)(bl + o + nt * 512);                       \
        }                                                                      \
        __builtin_amdgcn_sched_barrier(0);                                     \
    }

#define STAGEA(G, SLOT)                                                        \
    {                                                                          \
        const size_t go = (size_t)(G) * 64;                                    \
        GLD16(asrc[0] + go, &sA[w][SLOT][0 * 256]);                            \
        GLD16(asrc[1] + go, &sA[w][SLOT][1 * 256]);                            \
        GLD16(asrc[2] + go, &sA[w][SLOT][2 * 256]);                            \
        GLD16(asrc[3] + go, &sA[w][SLOT][3 * 256]);                            \
        __builtin_amdgcn_sched_barrier(0);                                     \
    }

#define WAITV(N)                                                               \
    {                                                                          \
        asm volatile("s_waitcnt vmcnt(" #N ")" ::: "memory");                  \
        __builtin_amdgcn_sched_barrier(0);                                     \
    }

#define KSTEP(SLOT, P, BH, BL)                                                 \
    {                                                                          \
        float4 a0 = *(const float4*)(rda + (SLOT) * 1024 + (P) * 32);          \
        float4 a1 = *(const float4*)(rdb + (SLOT) * 1024 + (P) * 32);          \
        half8 ah, al_;                                                         \
        cvt_hilo(a0, a1, ah, al_);                                             \
        _Pragma("unroll")                                                      \
        for (int nt = 0; nt < 4; ++nt) hh[nt] = MFMA16(ah, BH[nt], hh[nt]);    \
        _Pragma("unroll")                                                      \
        for (int nt = 0; nt < 4; ++nt) cc[nt] = MFMA16(ah, BL[nt], cc[nt]);    \
        _Pragma("unroll")                                                      \
        for (int nt = 0; nt < 4; ++nt) cc[nt] = MFMA16(al_, BH[nt], cc[nt]);   \
        __builtin_amdgcn_sched_barrier(0);                                     \
    }

    // ---- prologue: A groups 0,1; B ksteps 0,1,2 (outstanding = 32)
    STAGEA(0, 0) STAGEA(1, 1)
    LOADB(0, B0h, B0l) LOADB(1, B1h, B1l) LOADB(2, B2h, B2l)

    // t=0: completes A0,A1,B0 (leaves B1,B2); stage A2; B(3)->buf0
    WAITV(16) STAGEA(2, 2) KSTEP(0, 0, B0h, B0l) LOADB(3, B0h, B0l)

    // ---- steady: 20 iters x 6 ksteps (t = 6m+1 .. 6m+6), uniform vmcnt(20)
    for (int m = 0; m < 20; ++m) {
        const int t = 6 * m;
        WAITV(20)                    KSTEP(0, 1, B1h, B1l) LOADB(t + 4, B1h, B1l)
        WAITV(20) STAGEA(3 * m + 3, 0) KSTEP(1, 0, B2h, B2l) LOADB(t + 5, B2h, B2l)
        WAITV(20)                    KSTEP(1, 1, B0h, B0l) LOADB(t + 6, B0h, B0l)
        WAITV(20) STAGEA(3 * m + 4, 1) KSTEP(2, 0, B1h, B1l) LOADB(t + 7, B1h, B1l)
        WAITV(20)                    KSTEP(2, 1, B2h, B2l) LOADB(t + 8, B2h, B2l)
        WAITV(20) STAGEA(3 * m + 5, 2) KSTEP(0, 0, B0h, B0l) LOADB(t + 9, B0h, B0l)
    }

    // ---- tail: t = 121..127
    WAITV(20)               KSTEP(0, 1, B1h, B1l) LOADB(124, B1h, B1l)
    WAITV(20) STAGEA(63, 0) KSTEP(1, 0, B2h, B2l) LOADB(125, B2h, B2l)
    WAITV(20)               KSTEP(1, 1, B0h, B0l) LOADB(126, B0h, B0l)
    WAITV(20)               KSTEP(2, 0, B1h, B1l) LOADB(127, B1h, B1l)
    WAITV(16)               KSTEP(2, 1, B2h, B2l)
    WAITV(8)                KSTEP(0, 0, B0h, B0l)
    WAITV(0)                KSTEP(0, 1, B1h, B1l)

#undef LOADB
#undef STAGEA
#undef WAITV
#undef KSTEP

    // logits = (hh + cc*2^-12) * 2^-6; top-2 over 16-lane butterfly
    float tt[4][4];   // [nt][q]
    #pragma unroll
    for (int nt = 0; nt < 4; ++nt) {
        f32x4 tot = (hh[nt] + cc[nt] * (1.0f / 4096.0f)) * (1.0f / 64.0f);
        tt[nt][0] = tot.x; tt[nt][1] = tot.y; tt[nt][2] = tot.z; tt[nt][3] = tot.w;
    }

    float* out_e = out + (size_t)2 * ntok;

    #pragma unroll
    for (int q = 0; q < 4; ++q) {
        // C/D layout: col = lane&15 (expert sub), row = (lane>>4)*4 + q (token)
        float v1 = -3.0e38f, v2 = -3.0e38f;
        int   i1 = 1 << 30,  i2 = 1 << 30;
        #pragma unroll
        for (int nt = 0; nt < 4; ++nt) {
            float v  = tt[nt][q];
            int   id = nt * 16 + (l & 15);
            if (v > v1 || (v == v1 && id < i1)) {
                v2 = v1; i2 = i1; v1 = v; i1 = id;
            } else if (v > v2 || (v == v2 && id < i2)) {
                v2 = v; i2 = id;
            }
        }
        #pragma unroll
        for (int m = 1; m < 16; m <<= 1) {
            float ov1 = __shfl_xor(v1, m, 64);
            int   oi1 = __shfl_xor(i1, m, 64);
            float ov2 = __shfl_xor(v2, m, 64);
            int   oi2 = __shfl_xor(i2, m, 64);
            bool ofirst = (ov1 > v1) || (ov1 == v1 && oi1 < i1);
            if (ofirst) {
                bool s2 = (ov2 > v1) || (ov2 == v1 && oi2 < i1);
                v2 = s2 ? ov2 : v1;  i2 = s2 ? oi2 : i1;
                v1 = ov1;            i1 = oi1;
            } else {
                bool s2 = (ov1 > v2) || (ov1 == v2 && oi1 < i2);
                v2 = s2 ? ov1 : v2;  i2 = s2 ? oi1 : i2;
            }
        }

        if ((l & 15) == 0) {
            const int tok = tok0 + w * 16 + (l >> 4) * 4 + q;
            float e = expf(v2 - v1);     // <= 1
            float d = 1.0f + e;
            out[2 * tok + 0] = 1.0f / d;
            out[2 * tok + 1] = e / d;
            out_e[2 * tok + 0] = (float)i1;
            out_e[2 * tok + 1] = (float)i2;
        }
    }
}

extern "C" void kernel_launch(void* const* d_in, const int* in_sizes, int n_in,
                              void* d_out, int out_size, void* d_ws, size_t ws_size,
                              hipStream_t stream) {
    const float* x = (const float*)d_in[0];
    const float* W = (const float*)d_in[1];
    float* out = (float*)d_out;
    const int ntok = in_sizes[0] / D_MODEL;   // 32768

    _Float16* whf = (_Float16*)d_ws;                           // 512 KB
    _Float16* wlf = (_Float16*)d_ws + (size_t)N_EXP * D_MODEL; // 512 KB

    wprep_kernel<<<dim3(128), dim3(256), 0, stream>>>(W, whf, wlf);
    router_kernel<<<dim3(ntok / 64), dim3(256), 0, stream>>>(x, whf, wlf, out, ntok);
}

// Round 13
// 135.924 us; speedup vs baseline: 1.2811x; 1.2811x over previous
//
#include <hip/hip_runtime.h>
#include <math.h>

#define D_MODEL 4096
#define N_EXP   64

typedef _Float16 half8 __attribute__((ext_vector_type(8)));
typedef float    f32x4 __attribute__((ext_vector_type(4)));

// ---------------------------------------------------------------------------
// Prep: W[64][4096] fp32 -> fragment-ordered fp16 hi/lo arrays (in d_ws).
// Ws = W*64; hi = fp16(Ws); lo = fp16((Ws-hi)*4096). Fragment order:
// element (kstep,nt,lane,j) at ((kstep*4+nt)*64+lane)*8+j, expert
// e = nt*16+(lane&15), k = kstep*32+(lane>>4)*8+j. (Verified R4-R12.)
// ---------------------------------------------------------------------------
__global__ __launch_bounds__(256)
void wprep_kernel(const float* __restrict__ W,
                  _Float16* __restrict__ whf, _Float16* __restrict__ wlf) {
    const int gid   = blockIdx.x * 256 + threadIdx.x;   // 0..32767
    const int lane  = gid & 63;
    const int ntk   = gid >> 6;
    const int nt    = ntk & 3;
    const int kstep = ntk >> 2;
    const int e  = nt * 16 + (lane & 15);
    const int k0 = kstep * 32 + (lane >> 4) * 8;

    const float* src = W + (size_t)e * D_MODEL + k0;
    float4 w0 = *(const float4*)(src);
    float4 w1 = *(const float4*)(src + 4);
    float wv[8] = {w0.x, w0.y, w0.z, w0.w, w1.x, w1.y, w1.z, w1.w};

    half8 hh, ll;
    #pragma unroll
    for (int j = 0; j < 8; ++j) {
        float ws = wv[j] * 64.0f;
        _Float16 h = (_Float16)ws;
        hh[j] = h;
        ll[j] = (_Float16)((ws - (float)h) * 4096.0f);
    }
    *(half8*)(whf + (size_t)gid * 8) = hh;
    *(half8*)(wlf + (size_t)gid * 8) = ll;
}

// global -> LDS direct (16B/lane, dest = wave-uniform base + lane*16)
#define GLD16(gp, lp) __builtin_amdgcn_global_load_lds( \
    (const __attribute__((address_space(1))) unsigned int*)(const void*)(gp), \
    (__attribute__((address_space(3))) unsigned int*)(void*)(lp), 16, 0, 0)

__device__ __forceinline__ void cvt_hilo(const float4 a, const float4 b,
                                         half8& hi, half8& lo) {
    float av[8] = {a.x, a.y, a.z, a.w, b.x, b.y, b.z, b.w};
    #pragma unroll
    for (int j = 0; j < 8; ++j) {
        _Float16 h = (_Float16)av[j];
        hi[j] = h;
        lo[j] = (_Float16)((av[j] - (float)h) * 4096.0f);
    }
}

#define MFMA16(A, B, C) __builtin_amdgcn_mfma_f32_16x16x32_f16(A, B, C, 0, 0, 0)

// ---------------------------------------------------------------------------
// Main: 512 thr = 8 waves; wave = (strip 0-3, khalf 0-1): 16 tokens x 2048 k.
// 512 blocks -> 2 blocks/CU = 16 WAVES/CU (2x every prior round). B staged
// per khalf in sB (2-kstep dbuf, 64 KiB); barrier = s_waitcnt vmcnt(4) +
// raw s_barrier: drains only last group's L2 B-stage (aged 1 group), keeps
// this group's 4 HBM A-refills in flight (their waits are compiler-inserted
// at use, per-wave, off the barrier path). Epilogue: khalf partials combined
// through LDS (R4-verified), then 16-lane butterfly top-2.
// ---------------------------------------------------------------------------
__global__ __launch_bounds__(512, 4)
void router_kernel(const float* __restrict__ x,
                   const _Float16* __restrict__ whf,
                   const _Float16* __restrict__ wlf,
                   float* __restrict__ out, int ntok) {
    __shared__ __align__(16) _Float16 sB[2][2][2][2][4][512]; // [kh][buf][ksl][hl][nt][l*8] = 64 KiB

    const int tid  = threadIdx.x;
    const int w    = tid >> 6;
    const int l    = tid & 63;
    const int st   = w & 3;      // token strip
    const int kh   = w >> 2;     // k-half
    const int tok0 = blockIdx.x * 64;

    // A: lane l -> row tok0+st*16+(l&15), floats kh*2048 + t*32 + (l>>4)*8
    const float* ax = x + (size_t)(tok0 + st * 16 + (l & 15)) * D_MODEL
                        + kh * 2048 + (l >> 4) * 8;

    // B staging role: wave (kh,st) stages [kh][buf][ksl=st&1][hl=st>>1][nt0-3]
    const int ksl = st & 1;
    const int hl  = st >> 1;
    const _Float16* bsrc = (hl ? wlf : whf) + (size_t)(kh * 64) * 2048 + (size_t)l * 8;

    f32x4 hh[4], cc[4];
    #pragma unroll
    for (int nt = 0; nt < 4; ++nt) { hh[nt] = (f32x4)0.0f; cc[nt] = (f32x4)0.0f; }

    float4 R0a, R0b, R1a, R1b, R2a, R2b, R3a, R3b;   // ring: slot = t&3

#define STAGE(G, BUF)                                                          \
    {                                                                          \
        const size_t so = (size_t)(2 * (G) + ksl) * 2048;                      \
        GLD16(bsrc + so + 0 * 512, &sB[kh][BUF][ksl][hl][0][0]);               \
        GLD16(bsrc + so + 1 * 512, &sB[kh][BUF][ksl][hl][1][0]);               \
        GLD16(bsrc + so + 2 * 512, &sB[kh][BUF][ksl][hl][2][0]);               \
        GLD16(bsrc + so + 3 * 512, &sB[kh][BUF][ksl][hl][3][0]);               \
    }

#define REFILL(T, RA, RB)                                                      \
    {                                                                          \
        RA = *(const float4*)(ax + (size_t)(T) * 32);                          \
        RB = *(const float4*)(ax + (size_t)(T) * 32 + 4);                      \
    }

#define KSTEP(RA, RB, KSL_, BUF)                                               \
    {                                                                          \
        half8 ah, al_;                                                         \
        cvt_hilo(RA, RB, ah, al_);                                             \
        _Pragma("unroll")                                                      \
        for (int nt = 0; nt < 4; ++nt) {                                       \
            half8 bh = *(const half8*)&sB[kh][BUF][KSL_][0][nt][l * 8];        \
            half8 bl = *(const half8*)&sB[kh][BUF][KSL_][1][nt][l * 8];        \
            hh[nt] = MFMA16(ah, bh, hh[nt]);                                   \
            cc[nt] = MFMA16(ah, bl, cc[nt]);                                   \
            cc[nt] = MFMA16(al_, bh, cc[nt]);                                  \
        }                                                                      \
    }

#define SYNCN(N)                                                               \
    {                                                                          \
        asm volatile("s_waitcnt vmcnt(" #N ") lgkmcnt(0)" ::: "memory");       \
        __builtin_amdgcn_sched_barrier(0);                                     \
        __builtin_amdgcn_s_barrier();                                          \
        __builtin_amdgcn_sched_barrier(0);                                     \
    }

    // prologue: B group 0 -> buf0; ring t=0..3. vmcnt(8) completes the stage,
    // leaves the 8 ring loads in flight.
    STAGE(0, 0)
    REFILL(0, R0a, R0b) REFILL(1, R1a, R1b)
    REFILL(2, R2a, R2b) REFILL(3, R3a, R3b)
    SYNCN(8)

    // groups 0..29 (pairs). Group g: stage g+1, 2 ksteps, refill consumed
    // slots with t+4/t+5, counted barrier (keeps the 4 refills in flight).
    for (int g = 0; g < 30; g += 2) {
        STAGE(g + 1, 1)
        KSTEP(R0a, R0b, 0, 0)
        REFILL(2 * g + 4, R0a, R0b)
        KSTEP(R1a, R1b, 1, 0)
        REFILL(2 * g + 5, R1a, R1b)
        SYNCN(4)

        STAGE(g + 2, 0)
        KSTEP(R2a, R2b, 0, 1)
        REFILL(2 * g + 6, R2a, R2b)
        KSTEP(R3a, R3b, 1, 1)
        REFILL(2 * g + 7, R3a, R3b)
        SYNCN(4)
    }
    // g=30 (no refills left; drain stage(31) fully)
    STAGE(31, 1)
    KSTEP(R0a, R0b, 0, 0)
    KSTEP(R1a, R1b, 1, 0)
    SYNCN(0)
    // g=31 + pre-epilogue fence
    KSTEP(R2a, R2b, 0, 1)
    KSTEP(R3a, R3b, 1, 1)
    SYNCN(0)

#undef STAGE
#undef REFILL
#undef KSTEP
#undef SYNCN

    // partial logits (pre-descale): pt = hh + cc*2^-12
    f32x4 pt[4];
    #pragma unroll
    for (int nt = 0; nt < 4; ++nt) pt[nt] = hh[nt] + cc[nt] * (1.0f / 4096.0f);

    // combine k-halves through LDS (overlay on sB; all sB traffic fenced)
    float* red = (float*)&sB[0][0][0][0][0][0];   // 4KB per nt-plane x 4 = 16KB
    if (kh == 1) {
        #pragma unroll
        for (int nt = 0; nt < 4; ++nt)
            *(f32x4*)&red[(size_t)(nt * 256 + st * 64 + l) * 4] = pt[nt];
    }
    __syncthreads();
    if (kh == 1) return;

    float tt[4][4];   // [nt][q]
    #pragma unroll
    for (int nt = 0; nt < 4; ++nt) {
        f32x4 oth = *(const f32x4*)&red[(size_t)(nt * 256 + st * 64 + l) * 4];
        f32x4 tot = (pt[nt] + oth) * (1.0f / 64.0f);
        tt[nt][0] = tot.x; tt[nt][1] = tot.y; tt[nt][2] = tot.z; tt[nt][3] = tot.w;
    }

    float* out_e = out + (size_t)2 * ntok;

    #pragma unroll
    for (int q = 0; q < 4; ++q) {
        // C/D layout: col = lane&15 (expert sub), row = (lane>>4)*4 + q (token)
        float v1 = -3.0e38f, v2 = -3.0e38f;
        int   i1 = 1 << 30,  i2 = 1 << 30;
        #pragma unroll
        for (int nt = 0; nt < 4; ++nt) {
            float v  = tt[nt][q];
            int   id = nt * 16 + (l & 15);
            if (v > v1 || (v == v1 && id < i1)) {
                v2 = v1; i2 = i1; v1 = v; i1 = id;
            } else if (v > v2 || (v == v2 && id < i2)) {
                v2 = v; i2 = id;
            }
        }
        #pragma unroll
        for (int m = 1; m < 16; m <<= 1) {
            float ov1 = __shfl_xor(v1, m, 64);
            int   oi1 = __shfl_xor(i1, m, 64);
            float ov2 = __shfl_xor(v2, m, 64);
            int   oi2 = __shfl_xor(i2, m, 64);
            bool ofirst = (ov1 > v1) || (ov1 == v1 && oi1 < i1);
            if (ofirst) {
                bool s2 = (ov2 > v1) || (ov2 == v1 && oi2 < i1);
                v2 = s2 ? ov2 : v1;  i2 = s2 ? oi2 : i1;
                v1 = ov1;            i1 = oi1;
            } else {
                bool s2 = (ov1 > v2) || (ov1 == v2 && oi1 < i2);
                v2 = s2 ? ov1 : v2;  i2 = s2 ? oi1 : i2;
            }
        }

        if ((l & 15) == 0) {
            const int tok = tok0 + st * 16 + (l >> 4) * 4 + q;
            float e = expf(v2 - v1);     // <= 1
            float d = 1.0f + e;
            out[2 * tok + 0] = 1.0f / d;
            out[2 * tok + 1] = e / d;
            out_e[2 * tok + 0] = (float)i1;
            out_e[2 * tok + 1] = (float)i2;
        }
    }
}

extern "C" void kernel_launch(void* const* d_in, const int* in_sizes, int n_in,
                              void* d_out, int out_size, void* d_ws, size_t ws_size,
                              hipStream_t stream) {
    const float* x = (const float*)d_in[0];
    const float* W = (const float*)d_in[1];
    float* out = (float*)d_out;
    const int ntok = in_sizes[0] / D_MODEL;   // 32768

    _Float16* whf = (_Float16*)d_ws;                           // 512 KB
    _Float16* wlf = (_Float16*)d_ws + (size_t)N_EXP * D_MODEL; // 512 KB

    wprep_kernel<<<dim3(128), dim3(256), 0, stream>>>(W, whf, wlf);
    router_kernel<<<dim3(ntok / 64), dim3(512), 0, stream>>>(x, whf, wlf, out, ntok);
}

// Round 15
// 129.785 us; speedup vs baseline: 1.3417x; 1.0473x over previous
//
#include <hip/hip_runtime.h>
#include <math.h>

#define D_MODEL 4096
#define N_EXP   64

typedef _Float16 half8 __attribute__((ext_vector_type(8)));
typedef float    f32x4 __attribute__((ext_vector_type(4)));

// ---------------------------------------------------------------------------
// Prep: W[64][4096] fp32 -> fragment-ordered fp16 hi/lo arrays (in d_ws).
// Ws = W*64; hi = fp16(Ws); lo = fp16((Ws-hi)*4096). Fragment order:
// element (kstep,nt,lane,j) at ((kstep*4+nt)*64+lane)*8+j, expert
// e = nt*16+(lane&15), k = kstep*32+(lane>>4)*8+j. (Verified R4-R13.)
// ---------------------------------------------------------------------------
__global__ __launch_bounds__(256)
void wprep_kernel(const float* __restrict__ W,
                  _Float16* __restrict__ whf, _Float16* __restrict__ wlf) {
    const int gid   = blockIdx.x * 256 + threadIdx.x;   // 0..32767
    const int lane  = gid & 63;
    const int ntk   = gid >> 6;
    const int nt    = ntk & 3;
    const int kstep = ntk >> 2;
    const int e  = nt * 16 + (lane & 15);
    const int k0 = kstep * 32 + (lane >> 4) * 8;

    const float* src = W + (size_t)e * D_MODEL + k0;
    float4 w0 = *(const float4*)(src);
    float4 w1 = *(const float4*)(src + 4);
    float wv[8] = {w0.x, w0.y, w0.z, w0.w, w1.x, w1.y, w1.z, w1.w};

    half8 hh, ll;
    #pragma unroll
    for (int j = 0; j < 8; ++j) {
        float ws = wv[j] * 64.0f;
        _Float16 h = (_Float16)ws;
        hh[j] = h;
        ll[j] = (_Float16)((ws - (float)h) * 4096.0f);
    }
    *(half8*)(whf + (size_t)gid * 8) = hh;
    *(half8*)(wlf + (size_t)gid * 8) = ll;
}

// global -> LDS direct (16B/lane, linear lane*16 dest = our fragment layout)
#define GLD16(gp, lp) __builtin_amdgcn_global_load_lds( \
    (const __attribute__((address_space(1))) unsigned int*)(const void*)(gp), \
    (__attribute__((address_space(3))) unsigned int*)(void*)(lp), 16, 0, 0)

__device__ __forceinline__ void cvt_hilo(const float4 a, const float4 b,
                                         half8& hi, half8& lo) {
    float av[8] = {a.x, a.y, a.z, a.w, b.x, b.y, b.z, b.w};
    #pragma unroll
    for (int j = 0; j < 8; ++j) {
        _Float16 h = (_Float16)av[j];
        hi[j] = h;
        lo[j] = (_Float16)((av[j] - (float)h) * 4096.0f);
    }
}

// ---------------------------------------------------------------------------
// Main (R7 structure, best verified: 129.5us): 256 thr = 4 waves x 16 tokens
// = 64 tokens/block, 512 blocks (2/CU -> barrier drains in one block are
// covered by the other). B double-buffered in LDS, groups of 4 ksteps
// (64 KiB). A: depth-8 named-register ring; refills issue at group START
// (all loads >=1 group old at the barrier -> cheap vmcnt drain).
// ---------------------------------------------------------------------------
__global__ __launch_bounds__(256, 2)
void router_kernel(const float* __restrict__ x,
                   const _Float16* __restrict__ whf,
                   const _Float16* __restrict__ wlf,
                   float* __restrict__ out, int ntok) {
    __shared__ _Float16 sB[2][4][2][4][512];   // [buf][ksl][hi/lo][nt][lane*8] = 64 KiB

    const int tid  = threadIdx.x;
    const int w    = tid >> 6;    // wave 0..3 -> token strip & staged ksl
    const int l    = tid & 63;
    const int tok0 = blockIdx.x * 64;
    const float* ax = x + (size_t)(tok0 + w * 16 + (l & 15)) * D_MODEL + (l >> 4) * 8;

    f32x4 hh[4], cc[4];
    #pragma unroll
    for (int nt = 0; nt < 4; ++nt) { hh[nt] = (f32x4)0.0f; cc[nt] = (f32x4)0.0f; }

    // prologue: stage B group 0 into buf0 (wave w stages ksl=w)
    {
        const size_t co = (size_t)w * 4 * 512 + (size_t)l * 8;
        #pragma unroll
        for (int nt = 0; nt < 4; ++nt) {
            GLD16(whf + co + nt * 512, &sB[0][w][0][nt][0]);
            GLD16(wlf + co + nt * 512, &sB[0][w][1][nt][0]);
        }
    }
    // A-ring prologue: half0 = ks0-3, half1 = ks4-7
    float4 P0a = *(const float4*)(ax + 0 * 32), P0b = *(const float4*)(ax + 0 * 32 + 4);
    float4 P1a = *(const float4*)(ax + 1 * 32), P1b = *(const float4*)(ax + 1 * 32 + 4);
    float4 P2a = *(const float4*)(ax + 2 * 32), P2b = *(const float4*)(ax + 2 * 32 + 4);
    float4 P3a = *(const float4*)(ax + 3 * 32), P3b = *(const float4*)(ax + 3 * 32 + 4);
    float4 P4a = *(const float4*)(ax + 4 * 32), P4b = *(const float4*)(ax + 4 * 32 + 4);
    float4 P5a = *(const float4*)(ax + 5 * 32), P5b = *(const float4*)(ax + 5 * 32 + 4);
    float4 P6a = *(const float4*)(ax + 6 * 32), P6b = *(const float4*)(ax + 6 * 32 + 4);
    float4 P7a = *(const float4*)(ax + 7 * 32), P7b = *(const float4*)(ax + 7 * 32 + 4);

    __syncthreads();

#define STEP(KSL, SA, SB, CUR)                                                 \
    {                                                                          \
        half8 ah, al;                                                          \
        cvt_hilo(SA, SB, ah, al);                                              \
        half8 bh[4], bl[4];                                                    \
        _Pragma("unroll")                                                      \
        for (int nt = 0; nt < 4; ++nt) {                                       \
            bh[nt] = *(const half8*)&sB[CUR][KSL][0][nt][l * 8];               \
            bl[nt] = *(const half8*)&sB[CUR][KSL][1][nt][l * 8];               \
        }                                                                      \
        _Pragma("unroll")                                                      \
        for (int nt = 0; nt < 4; ++nt)                                         \
            hh[nt] = __builtin_amdgcn_mfma_f32_16x16x32_f16(ah, bh[nt], hh[nt], 0, 0, 0); \
        _Pragma("unroll")                                                      \
        for (int nt = 0; nt < 4; ++nt)                                         \
            cc[nt] = __builtin_amdgcn_mfma_f32_16x16x32_f16(ah, bl[nt], cc[nt], 0, 0, 0); \
        _Pragma("unroll")                                                      \
        for (int nt = 0; nt < 4; ++nt)                                         \
            cc[nt] = __builtin_amdgcn_mfma_f32_16x16x32_f16(al, bh[nt], cc[nt], 0, 0, 0); \
    }

    // GROUP(g): consume buf CUR = g&1 (A-half CUR); at start, refill the half
    // consumed in group g-1 with group g+1's A data, and stage group g+1's B.
#define GROUP(G, CUR, C0a,C0b,C1a,C1b,C2a,C2b,C3a,C3b,                         \
                      O0a,O0b,O1a,O1b,O2a,O2b,O3a,O3b)                         \
    {                                                                          \
        if ((G) >= 1 && (G) <= 30) {                                           \
            const size_t kb = (size_t)((G) + 1) * 4 * 32;                      \
            O0a = *(const float4*)(ax + kb + 0 * 32);                          \
            O0b = *(const float4*)(ax + kb + 0 * 32 + 4);                      \
            O1a = *(const float4*)(ax + kb + 1 * 32);                          \
            O1b = *(const float4*)(ax + kb + 1 * 32 + 4);                      \
            O2a = *(const float4*)(ax + kb + 2 * 32);                          \
            O2b = *(const float4*)(ax + kb + 2 * 32 + 4);                      \
            O3a = *(const float4*)(ax + kb + 3 * 32);                          \
            O3b = *(const float4*)(ax + kb + 3 * 32 + 4);                      \
        }                                                                      \
        if ((G) < 31) {                                                        \
            const int ksg = ((G) + 1) * 4 + w;                                 \
            const size_t co = (size_t)ksg * 4 * 512 + (size_t)l * 8;           \
            _Pragma("unroll")                                                  \
            for (int nt = 0; nt < 4; ++nt) {                                   \
                GLD16(whf + co + nt * 512, &sB[(CUR) ^ 1][w][0][nt][0]);       \
                GLD16(wlf + co + nt * 512, &sB[(CUR) ^ 1][w][1][nt][0]);       \
            }                                                                  \
        }                                                                      \
        STEP(0, C0a, C0b, CUR)                                                 \
        STEP(1, C1a, C1b, CUR)                                                 \
        STEP(2, C2a, C2b, CUR)                                                 \
        STEP(3, C3a, C3b, CUR)                                                 \
        __syncthreads();                                                       \
    }

    for (int gg = 0; gg < 16; ++gg) {
        const int g0 = gg * 2;
        GROUP(g0,     0, P0a,P0b,P1a,P1b,P2a,P2b,P3a,P3b,
                         P4a,P4b,P5a,P5b,P6a,P6b,P7a,P7b)
        GROUP(g0 + 1, 1, P4a,P4b,P5a,P5b,P6a,P6b,P7a,P7b,
                         P0a,P0b,P1a,P1b,P2a,P2b,P3a,P3b)
    }
#undef GROUP
#undef STEP

    // logits = (hh + cc*2^-12) * 2^-6; top-2 over 16-lane butterfly
    float tt[4][4];   // [nt][q]
    #pragma unroll
    for (int nt = 0; nt < 4; ++nt) {
        f32x4 tot = (hh[nt] + cc[nt] * (1.0f / 4096.0f)) * (1.0f / 64.0f);
        tt[nt][0] = tot.x; tt[nt][1] = tot.y; tt[nt][2] = tot.z; tt[nt][3] = tot.w;
    }

    float* out_e = out + (size_t)2 * ntok;

    #pragma unroll
    for (int q = 0; q < 4; ++q) {
        // C/D layout: col = lane&15 (expert sub), row = (lane>>4)*4 + q (token)
        float v1 = -3.0e38f, v2 = -3.0e38f;
        int   i1 = 1 << 30,  i2 = 1 << 30;
        #pragma unroll
        for (int nt = 0; nt < 4; ++nt) {
            float v  = tt[nt][q];
            int   id = nt * 16 + (l & 15);
            if (v > v1 || (v == v1 && id < i1)) {
                v2 = v1; i2 = i1; v1 = v; i1 = id;
            } else if (v > v2 || (v == v2 && id < i2)) {
                v2 = v; i2 = id;
            }
        }
        #pragma unroll
        for (int m = 1; m < 16; m <<= 1) {
            float ov1 = __shfl_xor(v1, m, 64);
            int   oi1 = __shfl_xor(i1, m, 64);
            float ov2 = __shfl_xor(v2, m, 64);
            int   oi2 = __shfl_xor(i2, m, 64);
            bool ofirst = (ov1 > v1) || (ov1 == v1 && oi1 < i1);
            if (ofirst) {
                bool s2 = (ov2 > v1) || (ov2 == v1 && oi2 < i1);
                v2 = s2 ? ov2 : v1;  i2 = s2 ? oi2 : i1;
                v1 = ov1;            i1 = oi1;
            } else {
                bool s2 = (ov1 > v2) || (ov1 == v2 && oi1 < i2);
                v2 = s2 ? ov1 : v2;  i2 = s2 ? oi1 : i2;
            }
        }

        if ((l & 15) == 0) {
            const int tok = tok0 + w * 16 + (l >> 4) * 4 + q;
            float e = expf(v2 - v1);     // <= 1
            float d = 1.0f + e;
            out[2 * tok + 0] = 1.0f / d;
            out[2 * tok + 1] = e / d;
            out_e[2 * tok + 0] = (float)i1;
            out_e[2 * tok + 1] = (float)i2;
        }
    }
}

extern "C" void kernel_launch(void* const* d_in, const int* in_sizes, int n_in,
                              void* d_out, int out_size, void* d_ws, size_t ws_size,
                              hipStream_t stream) {
    const float* x = (const float*)d_in[0];
    const float* W = (const float*)d_in[1];
    float* out = (float*)d_out;
    const int ntok = in_sizes[0] / D_MODEL;   // 32768

    _Float16* whf = (_Float16*)d_ws;                           // 512 KB
    _Float16* wlf = (_Float16*)d_ws + (size_t)N_EXP * D_MODEL; // 512 KB

    wprep_kernel<<<dim3(128), dim3(256), 0, stream>>>(W, whf, wlf);
    router_kernel<<<dim3(ntok / 64), dim3(256), 0, stream>>>(x, whf, wlf, out, ntok);
}